// Round 1
// baseline (7962.070 us; speedup 1.0000x reference)
//
#include <hip/hip_runtime.h>

// Problem constants (fixed by reference)
constexpr int N_ = 2, T_ = 12, C_ = 64, H_ = 112, W_ = 112;
constexpr int HW_ = H_ * W_;
constexpr float SLOPE_ = 0.1f;

// ---------------------------------------------------------------------------
// Bilinear sample with zero padding outside (matches reference flow_warp:
// per-corner validity mask, clipped gather index).
// ---------------------------------------------------------------------------
__device__ __forceinline__ float samp_one(const float* __restrict__ img, int y, int x) {
  if ((unsigned)x < (unsigned)W_ && (unsigned)y < (unsigned)H_)
    return img[y * W_ + x];
  return 0.f;
}

__device__ __forceinline__ float bilin(const float* __restrict__ img, float vx, float vy) {
  float x0f = floorf(vx), y0f = floorf(vy);
  int x0 = (int)x0f, y0 = (int)y0f;
  float wx = vx - x0f, wy = vy - y0f;
  float g00 = samp_one(img, y0,     x0);
  float g01 = samp_one(img, y0,     x0 + 1);
  float g10 = samp_one(img, y0 + 1, x0);
  float g11 = samp_one(img, y0 + 1, x0 + 1);
  return g00 * (1.f - wx) * (1.f - wy)
       + g01 * wx * (1.f - wy)
       + g10 * (1.f - wx) * wy
       + g11 * wx * wy;
}

// ---------------------------------------------------------------------------
// f2_tot = f1 + flow_warp(f2, f1)   (2 channels, per pixel)
// f1, f2 point at the t-slice; n-stride = T*2*HW. Output (N,2,HW).
// ---------------------------------------------------------------------------
__global__ __launch_bounds__(256) void f2tot_kernel(
    const float* __restrict__ f1, const float* __restrict__ f2,
    float* __restrict__ f2t) {
  int id = blockIdx.x * 256 + threadIdx.x;
  if (id >= N_ * HW_) return;
  int hw = id % HW_;
  int n  = id / HW_;
  int x = hw % W_, y = hw / W_;
  const float* f1n = f1 + (long)n * T_ * 2 * HW_;
  const float* f2n = f2 + (long)n * T_ * 2 * HW_;
  float vx = (float)x + f1n[hw];
  float vy = (float)y + f1n[HW_ + hw];
  float wfx = bilin(f2n,        vx, vy);
  float wfy = bilin(f2n + HW_,  vx, vy);
  f2t[((long)n * 2) * HW_ + hw]     = f1n[hw]       + wfx;
  f2t[((long)n * 2 + 1) * HW_ + hw] = f1n[HW_ + hw] + wfy;
}

// ---------------------------------------------------------------------------
// Build aggr (N, 3C, H, W): slot0 = curr, slot1 = warp(p1,f1) (or curr),
// slot2 = warp(p2, f2_tot) (or curr).
// curr/p1/p2 point at t-slices of the working feats; n-stride = T*C*HW.
// ---------------------------------------------------------------------------
__global__ __launch_bounds__(256) void build_aggr(
    const float* __restrict__ curr,
    const float* __restrict__ p1,      // may be null
    const float* __restrict__ p2,      // may be null
    const float* __restrict__ f1,      // may be null (t-slice, n-stride T*2*HW)
    const float* __restrict__ f2t,     // (N,2,HW) in ws
    float* __restrict__ aggr) {
  int id = blockIdx.x * 256 + threadIdx.x;
  if (id >= N_ * C_ * HW_) return;
  int hw = id % HW_;
  int c  = (id / HW_) % C_;
  int n  = id / (HW_ * C_);
  int x = hw % W_, y = hw / W_;
  long fn = (long)n * T_ * C_ * HW_;

  float cv = curr[fn + (long)c * HW_ + hw];
  float a1 = cv, a2 = cv;
  if (p1) {
    const float* f1n = f1 + (long)n * T_ * 2 * HW_;
    float vx = (float)x + f1n[hw];
    float vy = (float)y + f1n[HW_ + hw];
    a1 = bilin(p1 + fn + (long)c * HW_, vx, vy);
  }
  if (p2) {
    const float* ftn = f2t + (long)n * 2 * HW_;
    float vx = (float)x + ftn[hw];
    float vy = (float)y + ftn[HW_ + hw];
    a2 = bilin(p2 + fn + (long)c * HW_, vx, vy);
  }
  float* an = aggr + ((long)n * 3 * C_ + c) * HW_ + hw;
  an[0]                = cv;
  an[(long)C_ * HW_]   = a1;
  an[2L * C_ * HW_]    = a2;
}

// ---------------------------------------------------------------------------
// Direct 3x3 SAME conv, NCHW. Each block: 16x16 output tile, 8 output
// channels. Each thread: 1 pixel x 8 oc. Input staged in LDS ICB channels at
// a time; weight reads are block-uniform -> scalar loads (SGPR operand FMA).
// Optionally leaky-relu and/or residual add. out may alias nothing read here.
// ---------------------------------------------------------------------------
template <int IC, int ICB>
__global__ __launch_bounds__(256) void conv3x3(
    const float* __restrict__ in, long in_ns,      // n-stride (elements)
    const float* __restrict__ wgt,                 // (64, IC, 3, 3)
    const float* __restrict__ bias,                // (64)
    const float* __restrict__ resid, long res_ns,  // may be null
    float* __restrict__ out, long out_ns,
    int lrelu) {
  __shared__ float sm[ICB][18][18];
  int tx = threadIdx.x, ty = threadIdx.y;
  int bx = blockIdx.x * 16, by = blockIdx.y * 16;
  int zi = blockIdx.z;
  int ocg = zi % 8;      // 8 oc-groups of 8
  int n   = zi / 8;
  const float* inp = in + (long)n * in_ns;
  int oc0 = ocg * 8;
  int tid = ty * 16 + tx;

  float acc[8];
#pragma unroll
  for (int j = 0; j < 8; ++j) acc[j] = 0.f;

  for (int ic0 = 0; ic0 < IC; ic0 += ICB) {
    __syncthreads();
    for (int idx = tid; idx < ICB * 324; idx += 256) {
      int icl = idx / 324;
      int r   = idx - icl * 324;
      int sy  = r / 18, sx = r - sy * 18;
      int gy = by - 1 + sy, gx = bx - 1 + sx;
      float v = 0.f;
      if ((unsigned)gy < (unsigned)H_ && (unsigned)gx < (unsigned)W_)
        v = inp[(long)(ic0 + icl) * HW_ + gy * W_ + gx];
      sm[icl][sy][sx] = v;
    }
    __syncthreads();
#pragma unroll
    for (int icl = 0; icl < ICB; ++icl) {
      float v[9];
#pragma unroll
      for (int ky = 0; ky < 3; ++ky)
#pragma unroll
        for (int kx = 0; kx < 3; ++kx)
          v[ky * 3 + kx] = sm[icl][ty + ky][tx + kx];
      const float* wp = wgt + ((long)oc0 * IC + (ic0 + icl)) * 9;
#pragma unroll
      for (int j = 0; j < 8; ++j) {
        const float* wj = wp + (long)j * IC * 9;
#pragma unroll
        for (int k = 0; k < 9; ++k)
          acc[j] = fmaf(v[k], wj[k], acc[j]);
      }
    }
  }

  int oy = by + ty, ox = bx + tx;  // 7*16 == 112, always in range
  int hw = oy * W_ + ox;
#pragma unroll
  for (int j = 0; j < 8; ++j) {
    int oc = oc0 + j;
    float r = acc[j] + bias[oc];
    if (lrelu) r = (r > 0.f) ? r : r * SLOPE_;
    if (resid) r += resid[(long)n * res_ns + (long)oc * HW_ + hw];
    out[(long)n * out_ns + (long)oc * HW_ + hw] = r;
  }
}

// ---------------------------------------------------------------------------
// Host-side orchestration
// ---------------------------------------------------------------------------
static void run_step(float* out, const float* flows, int t, bool fwd, int i,
                     const float* W1, const float* b1,
                     const float* W2, const float* b2,
                     float* aggr, float* h1, float* f2t, hipStream_t stream) {
  const float* curr = out + (long)t * C_ * HW_;
  const float* p1 = nullptr;
  const float* p2 = nullptr;
  const float* f1 = nullptr;
  const float* f2 = nullptr;
  if (fwd) {
    if (t >= 1) { p1 = out + (long)(t - 1) * C_ * HW_; f1 = flows + (long)(t - 1) * 2 * HW_; }
    if (t >= 2) { p2 = out + (long)(t - 2) * C_ * HW_; f2 = flows + (long)(t - 2) * 2 * HW_; }
  } else {
    if (i >= 1) { p1 = out + (long)(t + 1) * C_ * HW_; f1 = flows + (long)(t + 1) * 2 * HW_; }
    if (i >= 2) { p2 = out + (long)(t + 2) * C_ * HW_; f2 = flows + (long)(t + 2) * 2 * HW_; }
  }

  if (p2) {
    int nb = (N_ * HW_ + 255) / 256;
    f2tot_kernel<<<nb, 256, 0, stream>>>(f1, f2, f2t);
  }
  {
    int nb = (N_ * C_ * HW_ + 255) / 256;
    build_aggr<<<nb, 256, 0, stream>>>(curr, p1, p2, f1, f2t, aggr);
  }
  // conv1: 192 -> 64, lrelu
  conv3x3<192, 4><<<dim3(7, 7, N_ * 8), dim3(16, 16), 0, stream>>>(
      aggr, (long)3 * C_ * HW_, W1, b1, nullptr, 0, h1, (long)C_ * HW_, 1);
  // conv2: 64 -> 64, + bias + residual(curr = aggr slot0), write into out[:, t]
  conv3x3<64, 4><<<dim3(7, 7, N_ * 8), dim3(16, 16), 0, stream>>>(
      h1, (long)C_ * HW_, W2, b2, aggr, (long)3 * C_ * HW_,
      out + (long)t * C_ * HW_, (long)T_ * C_ * HW_, 0);
}

extern "C" void kernel_launch(void* const* d_in, const int* in_sizes, int n_in,
                              void* d_out, int out_size, void* d_ws, size_t ws_size,
                              hipStream_t stream) {
  const float* feats = (const float*)d_in[0];
  const float* fflow = (const float*)d_in[1];
  const float* bflow = (const float*)d_in[2];
  const float* W1 = (const float*)d_in[3];
  const float* b1 = (const float*)d_in[4];
  const float* W2 = (const float*)d_in[5];
  const float* b2 = (const float*)d_in[6];
  float* out = (float*)d_out;

  float* aggr = (float*)d_ws;                           // N*3C*HW floats
  float* h1   = aggr + (size_t)N_ * 3 * C_ * HW_;       // N*C*HW floats
  float* f2t  = h1 + (size_t)N_ * C_ * HW_;             // N*2*HW floats

  // Seed the working feats (in d_out) with the input feats.
  hipMemcpyAsync(out, feats, sizeof(float) * (size_t)N_ * T_ * C_ * HW_,
                 hipMemcpyDeviceToDevice, stream);

  // Forward pass
  for (int t = 0; t < T_; ++t)
    run_step(out, fflow, t, true, t, W1, b1, W2, b2, aggr, h1, f2t, stream);
  // Backward pass
  for (int i = 0; i < T_; ++i) {
    int t = T_ - 1 - i;
    run_step(out, bflow, t, false, i, W1, b1, W2, b2, aggr, h1, f2t, stream);
  }
}

// Round 2
// 6491.511 us; speedup vs baseline: 1.2265x; 1.2265x over previous
//
#include <hip/hip_runtime.h>

// Problem constants (fixed by reference)
constexpr int N_ = 2, T_ = 12, C_ = 64, H_ = 112, W_ = 112;
constexpr int HW_ = H_ * W_;
constexpr float SLOPE_ = 0.1f;

// ---------------------------------------------------------------------------
// Bilinear sample with zero padding outside (matches reference flow_warp).
// ---------------------------------------------------------------------------
__device__ __forceinline__ float samp_one(const float* __restrict__ img, int y, int x) {
  if ((unsigned)x < (unsigned)W_ && (unsigned)y < (unsigned)H_)
    return img[y * W_ + x];
  return 0.f;
}

__device__ __forceinline__ float bilin(const float* __restrict__ img, float vx, float vy) {
  float x0f = floorf(vx), y0f = floorf(vy);
  int x0 = (int)x0f, y0 = (int)y0f;
  float wx = vx - x0f, wy = vy - y0f;
  float g00 = samp_one(img, y0,     x0);
  float g01 = samp_one(img, y0,     x0 + 1);
  float g10 = samp_one(img, y0 + 1, x0);
  float g11 = samp_one(img, y0 + 1, x0 + 1);
  return g00 * (1.f - wx) * (1.f - wy)
       + g01 * wx * (1.f - wy)
       + g10 * (1.f - wx) * wy
       + g11 * wx * wy;
}

// ---------------------------------------------------------------------------
// f2_tot = f1 + flow_warp(f2, f1)
// ---------------------------------------------------------------------------
__global__ __launch_bounds__(256) void f2tot_kernel(
    const float* __restrict__ f1, const float* __restrict__ f2,
    float* __restrict__ f2t) {
  int id = blockIdx.x * 256 + threadIdx.x;
  if (id >= N_ * HW_) return;
  int hw = id % HW_;
  int n  = id / HW_;
  int x = hw % W_, y = hw / W_;
  const float* f1n = f1 + (long)n * T_ * 2 * HW_;
  const float* f2n = f2 + (long)n * T_ * 2 * HW_;
  float vx = (float)x + f1n[hw];
  float vy = (float)y + f1n[HW_ + hw];
  float wfx = bilin(f2n,        vx, vy);
  float wfy = bilin(f2n + HW_,  vx, vy);
  f2t[((long)n * 2) * HW_ + hw]     = f1n[hw]       + wfx;
  f2t[((long)n * 2 + 1) * HW_ + hw] = f1n[HW_ + hw] + wfy;
}

// ---------------------------------------------------------------------------
// Build aggr (N, 3C, H, W): slot0 = curr, slot1 = warp(p1,f1), slot2 = warp(p2,f2t)
// ---------------------------------------------------------------------------
__global__ __launch_bounds__(256) void build_aggr(
    const float* __restrict__ curr,
    const float* __restrict__ p1,
    const float* __restrict__ p2,
    const float* __restrict__ f1,
    const float* __restrict__ f2t,
    float* __restrict__ aggr) {
  int id = blockIdx.x * 256 + threadIdx.x;
  if (id >= N_ * C_ * HW_) return;
  int hw = id % HW_;
  int c  = (id / HW_) % C_;
  int n  = id / (HW_ * C_);
  int x = hw % W_, y = hw / W_;
  long fn = (long)n * T_ * C_ * HW_;

  float cv = curr[fn + (long)c * HW_ + hw];
  float a1 = cv, a2 = cv;
  if (p1) {
    const float* f1n = f1 + (long)n * T_ * 2 * HW_;
    float vx = (float)x + f1n[hw];
    float vy = (float)y + f1n[HW_ + hw];
    a1 = bilin(p1 + fn + (long)c * HW_, vx, vy);
  }
  if (p2) {
    const float* ftn = f2t + (long)n * 2 * HW_;
    float vx = (float)x + ftn[hw];
    float vy = (float)y + ftn[HW_ + hw];
    a2 = bilin(p2 + fn + (long)c * HW_, vx, vy);
  }
  float* an = aggr + ((long)n * 3 * C_ + c) * HW_ + hw;
  an[0]                = cv;
  an[(long)C_ * HW_]   = a1;
  an[2L * C_ * HW_]    = a2;
}

// ---------------------------------------------------------------------------
// Weight transpose: (64, IC, 3, 3) -> (IC, 64, 9). Makes the 8-oc x 9 weight
// bundle for one input channel contiguous (single s_load_dwordx16 run).
// ---------------------------------------------------------------------------
__global__ __launch_bounds__(256) void transpose_w(
    const float* __restrict__ w, float* __restrict__ wt, int ic_total) {
  int id = blockIdx.x * 256 + threadIdx.x;
  int tot = 64 * ic_total * 9;
  if (id >= tot) return;
  int k  = id % 9;
  int ic = (id / 9) % ic_total;
  int oc = id / (9 * ic_total);
  wt[((long)ic * 64 + oc) * 9 + k] = w[id];
}

// ---------------------------------------------------------------------------
// Direct 3x3 SAME conv, NCHW, fp32 VALU.
// Block: 128 threads = 16x8 output tile, 8 output channels per block
// (blockIdx.z = n*8 + ocg). Double-buffered LDS staging of ICB=8 input
// channels (reg-staged, issued 2 chunks ahead, one barrier per chunk).
// Weights read from the transposed layout [ic][64][9] -> per-icl 72
// contiguous floats, block-uniform (scalar loads).
// ---------------------------------------------------------------------------
constexpr int TX = 16, TY = 8;          // output tile
constexpr int SX = 19;                  // padded LDS row stride (18 valid)
constexpr int ICB = 8;                  // input channels per chunk
constexpr int ELEMS = ICB * 10 * 18;    // staged elements per chunk = 1440
constexpr int NTHR = TX * TY;           // 128
constexpr int SITER = (ELEMS + NTHR - 1) / NTHR;  // 12

struct Stage {
  float v[SITER];
};

__device__ __forceinline__ void stage_load(Stage& s, const float* __restrict__ inp,
                                           int ic0, int by, int bx, int tid) {
#pragma unroll
  for (int i = 0; i < SITER; ++i) {
    int idx = tid + i * NTHR;
    float v = 0.f;
    if (idx < ELEMS) {
      int icl = idx / 180;
      int rem = idx - icl * 180;
      int sy  = rem / 18, sx = rem - sy * 18;
      int gy = by - 1 + sy, gx = bx - 1 + sx;
      if ((unsigned)gy < (unsigned)H_ && (unsigned)gx < (unsigned)W_)
        v = inp[(long)(ic0 + icl) * HW_ + gy * W_ + gx];
    }
    s.v[i] = v;
  }
}

__device__ __forceinline__ void stage_store(const Stage& s, float* __restrict__ smb,
                                            int tid) {
#pragma unroll
  for (int i = 0; i < SITER; ++i) {
    int idx = tid + i * NTHR;
    if (idx < ELEMS) {
      int icl = idx / 180;
      int rem = idx - icl * 180;
      int sy  = rem / 18, sx = rem - sy * 18;
      smb[(icl * 10 + sy) * SX + sx] = s.v[i];
    }
  }
}

template <int IC>
__global__ __launch_bounds__(NTHR) void conv3x3_v2(
    const float* __restrict__ in, long in_ns,
    const float* __restrict__ wt,              // transposed (IC, 64, 9)
    const float* __restrict__ bias,
    const float* __restrict__ resid, long res_ns,   // may be null
    float* __restrict__ out, long out_ns,
    int lrelu) {
  __shared__ float sm[2][ICB * 10 * SX];
  int tid = threadIdx.x;
  int tx = tid % TX, ty = tid / TX;
  int bx = blockIdx.x * TX, by = blockIdx.y * TY;
  int zi = blockIdx.z;
  int ocg = zi % 8;
  int n   = zi / 8;
  int oc0 = ocg * 8;
  const float* inp = in + (long)n * in_ns;

  constexpr int NCHUNK = IC / ICB;

  float acc[8];
#pragma unroll
  for (int j = 0; j < 8; ++j) acc[j] = 0.f;

  Stage s;
  stage_load(s, inp, 0, by, bx, tid);
  stage_store(s, sm[0], tid);
  if (NCHUNK > 1) stage_load(s, inp, ICB, by, bx, tid);

  for (int k = 0; k < NCHUNK; ++k) {
    __syncthreads();
    if (k + 1 < NCHUNK) {
      stage_store(s, sm[(k + 1) & 1], tid);
      if (k + 2 < NCHUNK) stage_load(s, inp, (k + 2) * ICB, by, bx, tid);
    }
    const float* smb = sm[k & 1];
    int ic0 = k * ICB;
#pragma unroll
    for (int icl = 0; icl < ICB; ++icl) {
      float v[9];
#pragma unroll
      for (int ky = 0; ky < 3; ++ky)
#pragma unroll
        for (int kx = 0; kx < 3; ++kx)
          v[ky * 3 + kx] = smb[(icl * 10 + ty + ky) * SX + tx + kx];
      const float* wp = wt + ((long)(ic0 + icl) * 64 + oc0) * 9;
#pragma unroll
      for (int j = 0; j < 8; ++j)
#pragma unroll
        for (int kk = 0; kk < 9; ++kk)
          acc[j] = fmaf(v[kk], wp[j * 9 + kk], acc[j]);
    }
  }

  int oy = by + ty, ox = bx + tx;   // 7*16==112, 14*8==112: always in range
  int hw = oy * W_ + ox;
#pragma unroll
  for (int j = 0; j < 8; ++j) {
    int oc = oc0 + j;
    float r = acc[j] + bias[oc];
    if (lrelu) r = (r > 0.f) ? r : r * SLOPE_;
    if (resid) r += resid[(long)n * res_ns + (long)oc * HW_ + hw];
    out[(long)n * out_ns + (long)oc * HW_ + hw] = r;
  }
}

// ---------------------------------------------------------------------------
// Host-side orchestration
// ---------------------------------------------------------------------------
static void run_step(float* out, const float* flows, int t, bool fwd, int i,
                     const float* W1t, const float* b1,
                     const float* W2t, const float* b2,
                     float* aggr, float* h1, float* f2t, hipStream_t stream) {
  const float* curr = out + (long)t * C_ * HW_;
  const float* p1 = nullptr;
  const float* p2 = nullptr;
  const float* f1 = nullptr;
  const float* f2 = nullptr;
  if (fwd) {
    if (t >= 1) { p1 = out + (long)(t - 1) * C_ * HW_; f1 = flows + (long)(t - 1) * 2 * HW_; }
    if (t >= 2) { p2 = out + (long)(t - 2) * C_ * HW_; f2 = flows + (long)(t - 2) * 2 * HW_; }
  } else {
    if (i >= 1) { p1 = out + (long)(t + 1) * C_ * HW_; f1 = flows + (long)(t + 1) * 2 * HW_; }
    if (i >= 2) { p2 = out + (long)(t + 2) * C_ * HW_; f2 = flows + (long)(t + 2) * 2 * HW_; }
  }

  if (p2) {
    int nb = (N_ * HW_ + 255) / 256;
    f2tot_kernel<<<nb, 256, 0, stream>>>(f1, f2, f2t);
  }
  {
    int nb = (N_ * C_ * HW_ + 255) / 256;
    build_aggr<<<nb, 256, 0, stream>>>(curr, p1, p2, f1, f2t, aggr);
  }
  // conv1: 192 -> 64, lrelu
  conv3x3_v2<192><<<dim3(7, 14, N_ * 8), NTHR, 0, stream>>>(
      aggr, (long)3 * C_ * HW_, W1t, b1, nullptr, 0, h1, (long)C_ * HW_, 1);
  // conv2: 64 -> 64, + bias + residual(curr copy in aggr slot0)
  conv3x3_v2<64><<<dim3(7, 14, N_ * 8), NTHR, 0, stream>>>(
      h1, (long)C_ * HW_, W2t, b2, aggr, (long)3 * C_ * HW_,
      out + (long)t * C_ * HW_, (long)T_ * C_ * HW_, 0);
}

extern "C" void kernel_launch(void* const* d_in, const int* in_sizes, int n_in,
                              void* d_out, int out_size, void* d_ws, size_t ws_size,
                              hipStream_t stream) {
  const float* feats = (const float*)d_in[0];
  const float* fflow = (const float*)d_in[1];
  const float* bflow = (const float*)d_in[2];
  const float* W1 = (const float*)d_in[3];
  const float* b1 = (const float*)d_in[4];
  const float* W2 = (const float*)d_in[5];
  const float* b2 = (const float*)d_in[6];
  float* out = (float*)d_out;

  float* aggr = (float*)d_ws;                            // N*3C*HW
  float* h1   = aggr + (size_t)N_ * 3 * C_ * HW_;        // N*C*HW
  float* f2t  = h1 + (size_t)N_ * C_ * HW_;              // N*2*HW
  float* W1t  = f2t + (size_t)N_ * 2 * HW_;              // 192*64*9
  float* W2t  = W1t + (size_t)192 * 64 * 9;              // 64*64*9

  // Transposed weights (once per launch; weights constant across steps).
  transpose_w<<<(64 * 192 * 9 + 255) / 256, 256, 0, stream>>>(W1, W1t, 192);
  transpose_w<<<(64 * 64 * 9 + 255) / 256, 256, 0, stream>>>(W2, W2t, 64);

  // Seed the working feats (in d_out) with the input feats.
  hipMemcpyAsync(out, feats, sizeof(float) * (size_t)N_ * T_ * C_ * HW_,
                 hipMemcpyDeviceToDevice, stream);

  // Forward pass
  for (int t = 0; t < T_; ++t)
    run_step(out, fflow, t, true, t, W1t, b1, W2t, b2, aggr, h1, f2t, stream);
  // Backward pass
  for (int i = 0; i < T_; ++i) {
    int t = T_ - 1 - i;
    run_step(out, bflow, t, false, i, W1t, b1, W2t, b2, aggr, h1, f2t, stream);
  }
}

// Round 4
// 2810.710 us; speedup vs baseline: 2.8328x; 2.3096x over previous
//
#include <hip/hip_runtime.h>

// Problem constants (fixed by reference)
constexpr int N_ = 2, T_ = 12, C_ = 64, H_ = 112, W_ = 112;
constexpr int HW_ = H_ * W_;
constexpr float SLOPE_ = 0.1f;
// Padded packed activation layout: rows -1..112 (114), cols -1..129 (131)
constexpr int PROW_ = 131;          // padded row length (x)
constexpr int PNROW_ = 114;         // padded row count (y)
constexpr int PPX_ = PROW_ * PNROW_; // 14934 pixels per (n, icb) slab

typedef short bf16x8 __attribute__((ext_vector_type(8)));
typedef float f32x16 __attribute__((ext_vector_type(16)));

__device__ __forceinline__ unsigned short f2bf(float f) {
  unsigned u = __float_as_uint(f);
  unsigned r = (u + 0x7fffu + ((u >> 16) & 1u)) >> 16;
  return (unsigned short)r;
}
__device__ __forceinline__ float bf2f(unsigned short h) {
  return __uint_as_float(((unsigned)h) << 16);
}

// ---------------------------------------------------------------------------
// Bilinear sample with zero padding outside (matches reference flow_warp).
// ---------------------------------------------------------------------------
__device__ __forceinline__ float samp_one(const float* __restrict__ img, int y, int x) {
  if ((unsigned)x < (unsigned)W_ && (unsigned)y < (unsigned)H_)
    return img[y * W_ + x];
  return 0.f;
}

__device__ __forceinline__ float bilin(const float* __restrict__ img, float vx, float vy) {
  float x0f = floorf(vx), y0f = floorf(vy);
  int x0 = (int)x0f, y0 = (int)y0f;
  float wx = vx - x0f, wy = vy - y0f;
  float g00 = samp_one(img, y0,     x0);
  float g01 = samp_one(img, y0,     x0 + 1);
  float g10 = samp_one(img, y0 + 1, x0);
  float g11 = samp_one(img, y0 + 1, x0 + 1);
  return g00 * (1.f - wx) * (1.f - wy)
       + g01 * wx * (1.f - wy)
       + g10 * (1.f - wx) * wy
       + g11 * wx * wy;
}

// ---------------------------------------------------------------------------
// f2_tot = f1 + flow_warp(f2, f1)
// ---------------------------------------------------------------------------
__global__ __launch_bounds__(256) void f2tot_kernel(
    const float* __restrict__ f1, const float* __restrict__ f2,
    float* __restrict__ f2t) {
  int id = blockIdx.x * 256 + threadIdx.x;
  if (id >= N_ * HW_) return;
  int hw = id % HW_;
  int n  = id / HW_;
  int x = hw % W_, y = hw / W_;
  const float* f1n = f1 + (long)n * T_ * 2 * HW_;
  const float* f2n = f2 + (long)n * T_ * 2 * HW_;
  float vx = (float)x + f1n[hw];
  float vy = (float)y + f1n[HW_ + hw];
  float wfx = bilin(f2n,        vx, vy);
  float wfy = bilin(f2n + HW_,  vx, vy);
  f2t[((long)n * 2) * HW_ + hw]     = f1n[hw]       + wfx;
  f2t[((long)n * 2 + 1) * HW_ + hw] = f1n[HW_ + hw] + wfy;
}

// ---------------------------------------------------------------------------
// Build aggr (N, 3C, H, W) fp32 NCHW: slot0=curr, slot1=warp(p1,f1), slot2=warp(p2,f2t)
// ---------------------------------------------------------------------------
__global__ __launch_bounds__(256) void build_aggr(
    const float* __restrict__ curr,
    const float* __restrict__ p1,
    const float* __restrict__ p2,
    const float* __restrict__ f1,
    const float* __restrict__ f2t,
    float* __restrict__ aggr) {
  int id = blockIdx.x * 256 + threadIdx.x;
  if (id >= N_ * C_ * HW_) return;
  int hw = id % HW_;
  int c  = (id / HW_) % C_;
  int n  = id / (HW_ * C_);
  int x = hw % W_, y = hw / W_;
  long fn = (long)n * T_ * C_ * HW_;

  float cv = curr[fn + (long)c * HW_ + hw];
  float a1 = cv, a2 = cv;
  if (p1) {
    const float* f1n = f1 + (long)n * T_ * 2 * HW_;
    float vx = (float)x + f1n[hw];
    float vy = (float)y + f1n[HW_ + hw];
    a1 = bilin(p1 + fn + (long)c * HW_, vx, vy);
  }
  if (p2) {
    const float* ftn = f2t + (long)n * 2 * HW_;
    float vx = (float)x + ftn[hw];
    float vy = (float)y + ftn[HW_ + hw];
    a2 = bilin(p2 + fn + (long)c * HW_, vx, vy);
  }
  float* an = aggr + ((long)n * 3 * C_ + c) * HW_ + hw;
  an[0]                = cv;
  an[(long)C_ * HW_]   = a1;
  an[2L * C_ * HW_]    = a2;
}

// ---------------------------------------------------------------------------
// pack_aggr: NCHW fp32 aggr -> padded packed hi/lo bf16 [n][12 icb][PPX][16ic].
// One block per (n, icb, row). Coalesced reads (112-px runs), LDS transpose,
// coalesced 16B writes. Pads stay zero (memset at launch start).
// ---------------------------------------------------------------------------
__global__ __launch_bounds__(256) void pack_aggr(
    const float* __restrict__ aggr, short* __restrict__ xhi, short* __restrict__ xlo) {
  __shared__ float sm[16][113];
  int bid = blockIdx.x;
  int y   = bid % H_;
  int icb = (bid / H_) % 12;
  int n   = bid / (H_ * 12);
  int tid = threadIdx.x;
  const float* src = aggr + ((long)(n * 192 + icb * 16)) * HW_ + y * W_;
  for (int i = tid; i < 16 * 112; i += 256) {
    int c = i / 112, x = i - c * 112;
    sm[c][x] = src[(long)c * HW_ + x];
  }
  __syncthreads();
  if (tid < 224) {
    int px = tid >> 1, gg = tid & 1;
    unsigned hh[8], ll[8];
#pragma unroll
    for (int j = 0; j < 8; ++j) {
      float v = sm[gg * 8 + j][px];
      hh[j] = f2bf(v);
      ll[j] = f2bf(v - bf2f((unsigned short)hh[j]));
    }
    long o = ((long)(n * 12 + icb) * PPX_ + (long)(y + 1) * PROW_ + (px + 1)) * 16 + gg * 8;
    uint4 uh, ul;
    uh.x = hh[0] | (hh[1] << 16); uh.y = hh[2] | (hh[3] << 16);
    uh.z = hh[4] | (hh[5] << 16); uh.w = hh[6] | (hh[7] << 16);
    ul.x = ll[0] | (ll[1] << 16); ul.y = ll[2] | (ll[3] << 16);
    ul.z = ll[4] | (ll[5] << 16); ul.w = ll[6] | (ll[7] << 16);
    *(uint4*)(xhi + o) = uh;
    *(uint4*)(xlo + o) = ul;
  }
}

// ---------------------------------------------------------------------------
// pack_w: W (64, IC, 3, 3) fp32 -> MFMA A-fragment order, split hi/lo bf16.
// Element id -> [mt][tap][icb][lane][r]: oc = mt*32+(lane&31),
// ic = icb*16 + (lane>>5)*8 + r, tap = ky*3+kx.
// ---------------------------------------------------------------------------
__global__ __launch_bounds__(256) void pack_w(
    const float* __restrict__ W, short* __restrict__ whi, short* __restrict__ wlo,
    int ICBC) {
  int id = blockIdx.x * 256 + threadIdx.x;
  int total = 2 * 9 * ICBC * 64 * 8;
  if (id >= total) return;
  int r    = id & 7;
  int lane = (id >> 3) & 63;
  int rest = id >> 9;                // (mt*9 + tap)*ICBC + icb
  int icb  = rest % ICBC;
  int mtt  = rest / ICBC;
  int tap  = mtt % 9;
  int mt   = mtt / 9;
  int oc = mt * 32 + (lane & 31);
  int ic = icb * 16 + ((lane >> 5) << 3) + r;
  int ky = tap / 3, kx = tap % 3;
  int IC = ICBC * 16;
  float v = W[(((long)oc * IC + ic) * 3 + ky) * 3 + kx];
  unsigned short h = f2bf(v);
  unsigned short l = f2bf(v - bf2f(h));
  whi[id] = (short)h;
  wlo[id] = (short)l;
}

// ---------------------------------------------------------------------------
// conv_mfma: 3x3 SAME conv via implicit-GEMM split-bf16 MFMA (32x32x16).
// Block = 128 thr (2 waves). Wave w: output row y=by*2+w, 32 px, all 64 oc
// (2 m-tiles). K loop: icb (16 ic) x 9 taps. Input: packed padded hi/lo.
// LDS: [2 dbuf][2 hl][4 rows][68 x 16B chunks], chunk order XOR-swizzled
// (pre-swizzled global src at stage + same swizzle on ds_read -> ~2-way banks).
// conv1 epilogue: bias+lrelu, split hi/lo -> packed padded out (conv2 input).
// conv2 epilogue: bias + residual, NCHW fp32 in-place on out[t].
// ---------------------------------------------------------------------------
template <int ICBC, bool IS1>
__global__ __launch_bounds__(128) void conv_mfma(
    const short* __restrict__ xhi, const short* __restrict__ xlo,
    const short* __restrict__ whi, const short* __restrict__ wlo,
    const float* __restrict__ bias,
    short* __restrict__ ohi, short* __restrict__ olo,  // conv1 out (packed, 4 icb)
    float* io) {                                       // conv2 in/out (NCHW t-slice)
  __shared__ alignas(16) short sm[2 * 4352];  // [dbuf][hl(2176)][row(544)][k*8]
  const int tid  = threadIdx.x;
  const int lane = tid & 63;
  const int w    = tid >> 6;
  const int g    = (lane >> 5) & 1;
  const int bx   = blockIdx.x * 32;
  const int by2  = blockIdx.y * 2;
  const int n    = blockIdx.z;

  f32x16 acc0, acc1;
#pragma unroll
  for (int i = 0; i < 16; ++i) { acc0[i] = 0.f; acc1[i] = 0.f; }

  uint4 stg[5];
  // chunk -> global source (inverse swizzle): c = [hl][row][k]
  auto stage_load = [&](int icb) {
#pragma unroll
    for (int i = 0; i < 5; ++i) {
      int c = tid + i * 128;
      bool ok = (c < 544);
      int cc = ok ? c : 0;
      int hl  = cc / 272;
      int rc  = cc - hl * 272;
      int row = rc / 68;
      int k   = rc - row * 68;
      int pxs = k >> 1, gp = k & 1;
      int px  = pxs ^ ((pxs >> 2) & 3);
      int gg  = gp ^ (px & 1);
      long off = ((long)(n * ICBC + icb) * PPX_ + (long)(by2 + row) * PROW_ + (bx + px)) * 16
               + gg * 8;
      const short* sp = hl ? xlo : xhi;
      uint4 v = {0, 0, 0, 0};
      if (ok) v = *(const uint4*)(sp + off);
      stg[i] = v;
    }
  };
  auto stage_write = [&](int buf) {
#pragma unroll
    for (int i = 0; i < 5; ++i) {
      int c = tid + i * 128;
      if (c < 544) *(uint4*)(sm + buf * 4352 + c * 8) = stg[i];
    }
  };

  // Prologue: stage icb 0 into buf 0
  stage_load(0);
  stage_write(0);
  __syncthreads();

  int cur = 0;
  for (int icb = 0; icb < ICBC; ++icb) {
    if (icb + 1 < ICBC) stage_load(icb + 1);   // issue next-tile loads early
    const short* smb = sm + cur * 4352;
#pragma unroll
    for (int tap = 0; tap < 9; ++tap) {
      const int dy = tap / 3, dx = tap % 3;
      int px  = (lane & 31) + dx;
      int pxs = px ^ ((px >> 2) & 3);
      int k   = (pxs << 1) | (g ^ (px & 1));
      const short* xb = smb + (w + dy) * 544 + k * 8;
      bf16x8 xh = *(const bf16x8*)xb;
      bf16x8 xl = *(const bf16x8*)(xb + 2176);
      long wi0 = ((long)((0 * 9 + tap) * ICBC + icb) * 64 + lane) * 8;
      long wi1 = ((long)((1 * 9 + tap) * ICBC + icb) * 64 + lane) * 8;
      bf16x8 wh0 = *(const bf16x8*)(whi + wi0);
      bf16x8 wl0 = *(const bf16x8*)(wlo + wi0);
      bf16x8 wh1 = *(const bf16x8*)(whi + wi1);
      bf16x8 wl1 = *(const bf16x8*)(wlo + wi1);
      acc0 = __builtin_amdgcn_mfma_f32_32x32x16_bf16(wh0, xh, acc0, 0, 0, 0);
      acc1 = __builtin_amdgcn_mfma_f32_32x32x16_bf16(wh1, xh, acc1, 0, 0, 0);
      acc0 = __builtin_amdgcn_mfma_f32_32x32x16_bf16(wl0, xh, acc0, 0, 0, 0);
      acc1 = __builtin_amdgcn_mfma_f32_32x32x16_bf16(wl1, xh, acc1, 0, 0, 0);
      acc0 = __builtin_amdgcn_mfma_f32_32x32x16_bf16(wh0, xl, acc0, 0, 0, 0);
      acc1 = __builtin_amdgcn_mfma_f32_32x32x16_bf16(wh1, xl, acc1, 0, 0, 0);
    }
    if (icb + 1 < ICBC) stage_write(cur ^ 1);  // write-late (loads drained by waitcnt)
    __syncthreads();
    cur ^= 1;
  }

  // Epilogue
  int pxg = bx + (lane & 31);
  int y   = by2 + w;
  if (pxg >= W_) return;
  if (IS1) {
#pragma unroll
    for (int mt = 0; mt < 2; ++mt) {
      const f32x16& A = mt ? acc1 : acc0;
#pragma unroll
      for (int rg = 0; rg < 4; ++rg) {
        int ocb = mt * 32 + rg * 8 + g * 4;
        float4 bv = *(const float4*)(bias + ocb);
        unsigned hh[4], ll[4];
#pragma unroll
        for (int j = 0; j < 4; ++j) {
          float t = A[rg * 4 + j] + ((const float*)&bv)[j];
          t = t > 0.f ? t : t * SLOPE_;
          hh[j] = f2bf(t);
          ll[j] = f2bf(t - bf2f((unsigned short)hh[j]));
        }
        int icb = mt * 2 + (rg >> 1);
        long o = ((long)(n * 4 + icb) * PPX_ + (long)(y + 1) * PROW_ + (pxg + 1)) * 16
               + (rg & 1) * 8 + g * 4;
        uint2 uh{hh[0] | (hh[1] << 16), hh[2] | (hh[3] << 16)};
        uint2 ul{ll[0] | (ll[1] << 16), ll[2] | (ll[3] << 16)};
        *(uint2*)(ohi + o) = uh;
        *(uint2*)(olo + o) = ul;
      }
    }
  } else {
    long base = (long)n * T_ * C_ * HW_ + (long)y * W_ + pxg;
#pragma unroll
    for (int mt = 0; mt < 2; ++mt) {
      const f32x16& A = mt ? acc1 : acc0;
#pragma unroll
      for (int rg = 0; rg < 4; ++rg) {
        int ocb = mt * 32 + rg * 8 + g * 4;
        float4 bv = *(const float4*)(bias + ocb);
#pragma unroll
        for (int j = 0; j < 4; ++j) {
          long o = base + (long)(ocb + j) * HW_;
          float r = io[o];  // residual (same thread reads then writes)
          io[o] = A[rg * 4 + j] + ((const float*)&bv)[j] + r;
        }
      }
    }
  }
}

// ---------------------------------------------------------------------------
// Host-side orchestration
// ---------------------------------------------------------------------------
struct Bufs {
  float* aggr; float* f2t;
  short *xhi, *xlo, *h1hi, *h1lo, *w1hi, *w1lo, *w2hi, *w2lo;
};

static void run_step(float* out, const float* flows, int t, bool fwd, int i,
                     const float* b1, const float* b2, const Bufs& B,
                     hipStream_t stream) {
  const float* curr = out + (long)t * C_ * HW_;
  const float* p1 = nullptr;
  const float* p2 = nullptr;
  const float* f1 = nullptr;
  const float* f2 = nullptr;
  if (fwd) {
    if (t >= 1) { p1 = out + (long)(t - 1) * C_ * HW_; f1 = flows + (long)(t - 1) * 2 * HW_; }
    if (t >= 2) { p2 = out + (long)(t - 2) * C_ * HW_; f2 = flows + (long)(t - 2) * 2 * HW_; }
  } else {
    if (i >= 1) { p1 = out + (long)(t + 1) * C_ * HW_; f1 = flows + (long)(t + 1) * 2 * HW_; }
    if (i >= 2) { p2 = out + (long)(t + 2) * C_ * HW_; f2 = flows + (long)(t + 2) * 2 * HW_; }
  }

  if (p2) {
    int nb = (N_ * HW_ + 255) / 256;
    f2tot_kernel<<<nb, 256, 0, stream>>>(f1, f2, B.f2t);
  }
  {
    int nb = (N_ * C_ * HW_ + 255) / 256;
    build_aggr<<<nb, 256, 0, stream>>>(curr, p1, p2, f1, B.f2t, B.aggr);
  }
  pack_aggr<<<N_ * 12 * H_, 256, 0, stream>>>(B.aggr, B.xhi, B.xlo);
  conv_mfma<12, true><<<dim3(4, 56, N_), 128, 0, stream>>>(
      B.xhi, B.xlo, B.w1hi, B.w1lo, b1, B.h1hi, B.h1lo, nullptr);
  conv_mfma<4, false><<<dim3(4, 56, N_), 128, 0, stream>>>(
      B.h1hi, B.h1lo, B.w2hi, B.w2lo, b2, nullptr, nullptr,
      out + (long)t * C_ * HW_);
}

extern "C" void kernel_launch(void* const* d_in, const int* in_sizes, int n_in,
                              void* d_out, int out_size, void* d_ws, size_t ws_size,
                              hipStream_t stream) {
  const float* feats = (const float*)d_in[0];
  const float* fflow = (const float*)d_in[1];
  const float* bflow = (const float*)d_in[2];
  const float* W1 = (const float*)d_in[3];
  const float* b1 = (const float*)d_in[4];
  const float* W2 = (const float*)d_in[5];
  const float* b2 = (const float*)d_in[6];
  float* out = (float*)d_out;

  char* p = (char*)d_ws;
  auto carve = [&](size_t bytes) {
    void* r = (void*)p;
    p += (bytes + 255) & ~(size_t)255;
    return r;
  };
  Bufs B;
  size_t xpack_sh  = (size_t)N_ * 12 * PPX_ * 16;  // shorts per hi (or lo)
  size_t h1pack_sh = (size_t)N_ * 4 * PPX_ * 16;
  B.aggr = (float*)carve(sizeof(float) * N_ * 3 * C_ * HW_);
  B.f2t  = (float*)carve(sizeof(float) * N_ * 2 * HW_);
  B.xhi  = (short*)carve(2 * xpack_sh);
  B.xlo  = (short*)carve(2 * xpack_sh);
  B.h1hi = (short*)carve(2 * h1pack_sh);
  B.h1lo = (short*)carve(2 * h1pack_sh);
  B.w1hi = (short*)carve(2 * (size_t)(2 * 9 * 12 * 64 * 8));
  B.w1lo = (short*)carve(2 * (size_t)(2 * 9 * 12 * 64 * 8));
  B.w2hi = (short*)carve(2 * (size_t)(2 * 9 * 4 * 64 * 8));
  B.w2lo = (short*)carve(2 * (size_t)(2 * 9 * 4 * 64 * 8));

  // Zero packed buffers once per launch (zeros the conv padding halos).
  hipMemsetAsync(B.xhi, 0, 2 * xpack_sh, stream);
  hipMemsetAsync(B.xlo, 0, 2 * xpack_sh, stream);
  hipMemsetAsync(B.h1hi, 0, 2 * h1pack_sh, stream);
  hipMemsetAsync(B.h1lo, 0, 2 * h1pack_sh, stream);

  // Weight fragments (hi/lo split), once per launch.
  pack_w<<<(2 * 9 * 12 * 64 * 8 + 255) / 256, 256, 0, stream>>>(W1, B.w1hi, B.w1lo, 12);
  pack_w<<<(2 * 9 * 4 * 64 * 8 + 255) / 256, 256, 0, stream>>>(W2, B.w2hi, B.w2lo, 4);

  // Seed the working feats (in d_out) with the input feats.
  hipMemcpyAsync(out, feats, sizeof(float) * (size_t)N_ * T_ * C_ * HW_,
                 hipMemcpyDeviceToDevice, stream);

  for (int t = 0; t < T_; ++t)
    run_step(out, fflow, t, true, t, b1, b2, B, stream);
  for (int i = 0; i < T_; ++i) {
    int t = T_ - 1 - i;
    run_step(out, bflow, t, false, i, b1, b2, B, stream);
  }
}

// Round 5
// 2165.846 us; speedup vs baseline: 3.6762x; 1.2977x over previous
//
#include <hip/hip_runtime.h>

// Problem constants (fixed by reference)
constexpr int N_ = 2, T_ = 12, C_ = 64, H_ = 112, W_ = 112;
constexpr int HW_ = H_ * W_;
constexpr float SLOPE_ = 0.1f;
// Padded packed activation layout: rows -1..112 (114), cols -1..129 (131)
constexpr int PROW_ = 131;
constexpr int PNROW_ = 114;
constexpr int PPX_ = PROW_ * PNROW_;

typedef short bf16x8 __attribute__((ext_vector_type(8)));
typedef float f32x16 __attribute__((ext_vector_type(16)));

__device__ __forceinline__ unsigned short f2bf(float f) {
  unsigned u = __float_as_uint(f);
  unsigned r = (u + 0x7fffu + ((u >> 16) & 1u)) >> 16;
  return (unsigned short)r;
}
__device__ __forceinline__ float bf2f(unsigned short h) {
  return __uint_as_float(((unsigned)h) << 16);
}

// ---------------------------------------------------------------------------
// Bilinear sample with zero padding outside (matches reference flow_warp).
// ---------------------------------------------------------------------------
__device__ __forceinline__ float samp_one(const float* __restrict__ img, int y, int x) {
  if ((unsigned)x < (unsigned)W_ && (unsigned)y < (unsigned)H_)
    return img[y * W_ + x];
  return 0.f;
}

__device__ __forceinline__ float bilin(const float* __restrict__ img, float vx, float vy) {
  float x0f = floorf(vx), y0f = floorf(vy);
  int x0 = (int)x0f, y0 = (int)y0f;
  float wx = vx - x0f, wy = vy - y0f;
  float g00 = samp_one(img, y0,     x0);
  float g01 = samp_one(img, y0,     x0 + 1);
  float g10 = samp_one(img, y0 + 1, x0);
  float g11 = samp_one(img, y0 + 1, x0 + 1);
  return g00 * (1.f - wx) * (1.f - wy)
       + g01 * wx * (1.f - wy)
       + g10 * (1.f - wx) * wy
       + g11 * wx * wy;
}

// ---------------------------------------------------------------------------
// f2_tot = f1 + flow_warp(f2, f1)
// ---------------------------------------------------------------------------
__global__ __launch_bounds__(256) void f2tot_kernel(
    const float* __restrict__ f1, const float* __restrict__ f2,
    float* __restrict__ f2t) {
  int id = blockIdx.x * 256 + threadIdx.x;
  if (id >= N_ * HW_) return;
  int hw = id % HW_;
  int n  = id / HW_;
  int x = hw % W_, y = hw / W_;
  const float* f1n = f1 + (long)n * T_ * 2 * HW_;
  const float* f2n = f2 + (long)n * T_ * 2 * HW_;
  float vx = (float)x + f1n[hw];
  float vy = (float)y + f1n[HW_ + hw];
  float wfx = bilin(f2n,        vx, vy);
  float wfy = bilin(f2n + HW_,  vx, vy);
  f2t[((long)n * 2) * HW_ + hw]     = f1n[hw]       + wfx;
  f2t[((long)n * 2 + 1) * HW_ + hw] = f1n[HW_ + hw] + wfy;
}

// ---------------------------------------------------------------------------
// warp_pack: fused build_aggr + pack_aggr. Block = (n, icb 0..11, row y).
// slot = icb/4 selects source: 0=curr copy, 1=warp(p1,f1), 2=warp(p2,f2t);
// falls back to curr when p1/p2 null. Output: padded packed hi/lo bf16
// [n][12][PPX][16ic]. Branch is block-uniform (safe syncthreads).
// ---------------------------------------------------------------------------
__global__ __launch_bounds__(256) void warp_pack(
    const float* __restrict__ curr,   // t-slice, n-stride T*C*HW
    const float* __restrict__ p1,     // may be null
    const float* __restrict__ p2,     // may be null
    const float* __restrict__ f1,     // t-slice, n-stride T*2*HW
    const float* __restrict__ f2t,    // (N,2,HW)
    short* __restrict__ xhi, short* __restrict__ xlo) {
  __shared__ float sm[16][113];
  __shared__ float sv[2][112];
  int bid = blockIdx.x;
  int y   = bid % H_;
  int icb = (bid / H_) % 12;
  int n   = bid / (H_ * 12);
  int tid = threadIdx.x;
  int slot = icb >> 2;
  int c0   = (icb & 3) * 16;
  long fn = (long)n * T_ * C_ * HW_;

  const float* src = nullptr;
  if (slot == 1 && p1) src = p1;
  if (slot == 2 && p2) src = p2;

  if (src == nullptr) {
    const float* cp = curr + fn + (long)c0 * HW_ + (long)y * W_;
    for (int i = tid; i < 16 * 112; i += 256) {
      int c = i / 112, x = i - c * 112;
      sm[c][x] = cp[(long)c * HW_ + x];
    }
  } else {
    if (tid < 112) {
      long hw = (long)y * W_ + tid;
      if (slot == 1) {
        const float* fp = f1 + (long)n * T_ * 2 * HW_;
        sv[0][tid] = (float)tid + fp[hw];
        sv[1][tid] = (float)y   + fp[HW_ + hw];
      } else {
        const float* fp = f2t + (long)n * 2 * HW_;
        sv[0][tid] = (float)tid + fp[hw];
        sv[1][tid] = (float)y   + fp[HW_ + hw];
      }
    }
    __syncthreads();
    const float* sp = src + fn + (long)c0 * HW_;
    for (int i = tid; i < 16 * 112; i += 256) {
      int c = i / 112, x = i - c * 112;
      sm[c][x] = bilin(sp + (long)c * HW_, sv[0][x], sv[1][x]);
    }
  }
  __syncthreads();
  if (tid < 224) {
    int px = tid >> 1, gg = tid & 1;
    unsigned hh[8], ll[8];
#pragma unroll
    for (int j = 0; j < 8; ++j) {
      float v = sm[gg * 8 + j][px];
      hh[j] = f2bf(v);
      ll[j] = f2bf(v - bf2f((unsigned short)hh[j]));
    }
    long o = ((long)(n * 12 + icb) * PPX_ + (long)(y + 1) * PROW_ + (px + 1)) * 16 + gg * 8;
    uint4 uh, ul;
    uh.x = hh[0] | (hh[1] << 16); uh.y = hh[2] | (hh[3] << 16);
    uh.z = hh[4] | (hh[5] << 16); uh.w = hh[6] | (hh[7] << 16);
    ul.x = ll[0] | (ll[1] << 16); ul.y = ll[2] | (ll[3] << 16);
    ul.z = ll[4] | (ll[5] << 16); ul.w = ll[6] | (ll[7] << 16);
    *(uint4*)(xhi + o) = uh;
    *(uint4*)(xlo + o) = ul;
  }
}

// ---------------------------------------------------------------------------
// pack_w: W (64, IC, 3, 3) fp32 -> MFMA A-fragment order, split hi/lo bf16.
// id -> [mt][tap][icb][lane][r]: oc = mt*32+(lane&31), ic = icb*16+(lane>>5)*8+r.
// ---------------------------------------------------------------------------
__global__ __launch_bounds__(256) void pack_w(
    const float* __restrict__ W, short* __restrict__ whi, short* __restrict__ wlo,
    int ICBC) {
  int id = blockIdx.x * 256 + threadIdx.x;
  int total = 2 * 9 * ICBC * 64 * 8;
  if (id >= total) return;
  int r    = id & 7;
  int lane = (id >> 3) & 63;
  int rest = id >> 9;
  int icb  = rest % ICBC;
  int mtt  = rest / ICBC;
  int tap  = mtt % 9;
  int mt   = mtt / 9;
  int oc = mt * 32 + (lane & 31);
  int ic = icb * 16 + ((lane >> 5) << 3) + r;
  int ky = tap / 3, kx = tap % 3;
  int IC = ICBC * 16;
  float v = W[(((long)oc * IC + ic) * 3 + ky) * 3 + kx];
  unsigned short h = f2bf(v);
  unsigned short l = f2bf(v - bf2f(h));
  whi[id] = (short)h;
  wlo[id] = (short)l;
}

// ---------------------------------------------------------------------------
// conv_mfma_p: 3x3 SAME conv partial via implicit-GEMM split-bf16 MFMA
// (32x32x16). Block = 256 thr (4 waves). Wave wid: mt = wid&1 (32 oc),
// row = wid>>1 (output row by2+row, 32 px). blockIdx.z = n*KG + kg;
// each kg reduces NICB=ICBT/KG input-channel blocks -> fp32 partial
// part[z][oc64][HW]. 3 independent acc chains (WhXh / WlXh / WhXl).
// LDS: shared 2-dbuf staging (4 rows x 34px x 16ic, hi+lo), XOR-swizzled
// chunk order (inverse swizzle on global src, forward on ds_read).
// ---------------------------------------------------------------------------
template <int ICBT, int KG>
__global__ __launch_bounds__(256, 4) void conv_mfma_p(
    const short* __restrict__ xhi, const short* __restrict__ xlo,
    const short* __restrict__ whi, const short* __restrict__ wlo,
    float* __restrict__ part) {
  constexpr int NICB = ICBT / KG;
  __shared__ alignas(16) short sm[2 * 4352];  // [dbuf][hl(2176)][row(544)][k*8]
  const int tid  = threadIdx.x;
  const int lane = tid & 63;
  const int wid  = tid >> 6;
  const int mt   = wid & 1;
  const int row  = wid >> 1;
  const int g    = (lane >> 5) & 1;
  const int bx   = blockIdx.x * 32;
  const int by2  = blockIdx.y * 2;
  const int z    = blockIdx.z;
  const int kg   = z % KG;
  const int n    = z / KG;
  const int icb0 = kg * NICB;

  f32x16 accA, accB, accC;
#pragma unroll
  for (int i = 0; i < 16; ++i) { accA[i] = 0.f; accB[i] = 0.f; accC[i] = 0.f; }

  uint4 stg[3];
  auto stage_load = [&](int icb) {
#pragma unroll
    for (int i = 0; i < 3; ++i) {
      int c = tid + i * 256;
      bool ok = (c < 544);
      int cc = ok ? c : 0;
      int hl  = cc / 272;
      int rc  = cc - hl * 272;
      int rw  = rc / 68;
      int k   = rc - rw * 68;
      int pxs = k >> 1, gp = k & 1;
      int px  = pxs ^ ((pxs >> 2) & 3);
      int gg  = gp ^ (px & 1);
      long off = ((long)(n * ICBT + icb) * PPX_ + (long)(by2 + rw) * PROW_ + (bx + px)) * 16
               + gg * 8;
      const short* sp = hl ? xlo : xhi;
      if (ok) stg[i] = *(const uint4*)(sp + off);
    }
  };
  auto stage_write = [&](int buf) {
#pragma unroll
    for (int i = 0; i < 3; ++i) {
      int c = tid + i * 256;
      if (c < 544) *(uint4*)(sm + buf * 4352 + c * 8) = stg[i];
    }
  };

  stage_load(icb0);
  stage_write(0);
  __syncthreads();

  int cur = 0;
  for (int ii = 0; ii < NICB; ++ii) {
    int icb = icb0 + ii;
    if (ii + 1 < NICB) stage_load(icb + 1);
    const short* smb = sm + cur * 4352;
#pragma unroll
    for (int tap = 0; tap < 9; ++tap) {
      const int dy = tap / 3, dx = tap % 3;
      int px  = (lane & 31) + dx;
      int pxs = px ^ ((px >> 2) & 3);
      int k   = (pxs << 1) | (g ^ (px & 1));
      const short* xb = smb + (row + dy) * 544 + k * 8;
      bf16x8 xh = *(const bf16x8*)xb;
      bf16x8 xl = *(const bf16x8*)(xb + 2176);
      long wi = ((long)((mt * 9 + tap) * ICBT + icb) * 64 + lane) * 8;
      bf16x8 wh = *(const bf16x8*)(whi + wi);
      bf16x8 wl = *(const bf16x8*)(wlo + wi);
      accA = __builtin_amdgcn_mfma_f32_32x32x16_bf16(wh, xh, accA, 0, 0, 0);
      accB = __builtin_amdgcn_mfma_f32_32x32x16_bf16(wl, xh, accB, 0, 0, 0);
      accC = __builtin_amdgcn_mfma_f32_32x32x16_bf16(wh, xl, accC, 0, 0, 0);
    }
    if (ii + 1 < NICB) stage_write(cur ^ 1);
    __syncthreads();
    cur ^= 1;
  }

  int pxg = bx + (lane & 31);
  int y   = by2 + row;
  if (pxg < W_) {
    long base = (long)z * 64 * HW_ + (long)y * W_ + pxg;
#pragma unroll
    for (int r = 0; r < 16; ++r) {
      int oc = mt * 32 + (r & 3) + 8 * (r >> 2) + 4 * g;
      part[base + (long)oc * HW_] = accA[r] + accB[r] + accC[r];
    }
  }
}

// ---------------------------------------------------------------------------
// combine1: h1 = lrelu(part[kg0]+part[kg1]+bias) -> packed padded hi/lo
// (conv2 input). Block = (n, icb 0..3, row y), pack_aggr-style LDS transpose.
// ---------------------------------------------------------------------------
__global__ __launch_bounds__(256) void combine1(
    const float* __restrict__ part, const float* __restrict__ bias,
    short* __restrict__ ohi, short* __restrict__ olo) {
  __shared__ float sm[16][113];
  int bid = blockIdx.x;
  int y   = bid % H_;
  int icb = (bid / H_) % 4;
  int n   = bid / (H_ * 4);
  int tid = threadIdx.x;
  for (int i = tid; i < 16 * 112; i += 256) {
    int c = i / 112, x = i - c * 112;
    int oc = icb * 16 + c;
    long hw = (long)y * W_ + x;
    float v = part[((long)(n * 2 + 0) * 64 + oc) * HW_ + hw]
            + part[((long)(n * 2 + 1) * 64 + oc) * HW_ + hw]
            + bias[oc];
    v = v > 0.f ? v : v * SLOPE_;
    sm[c][x] = v;
  }
  __syncthreads();
  if (tid < 224) {
    int px = tid >> 1, gg = tid & 1;
    unsigned hh[8], ll[8];
#pragma unroll
    for (int j = 0; j < 8; ++j) {
      float v = sm[gg * 8 + j][px];
      hh[j] = f2bf(v);
      ll[j] = f2bf(v - bf2f((unsigned short)hh[j]));
    }
    long o = ((long)(n * 4 + icb) * PPX_ + (long)(y + 1) * PROW_ + (px + 1)) * 16 + gg * 8;
    uint4 uh, ul;
    uh.x = hh[0] | (hh[1] << 16); uh.y = hh[2] | (hh[3] << 16);
    uh.z = hh[4] | (hh[5] << 16); uh.w = hh[6] | (hh[7] << 16);
    ul.x = ll[0] | (ll[1] << 16); ul.y = ll[2] | (ll[3] << 16);
    ul.z = ll[4] | (ll[5] << 16); ul.w = ll[6] | (ll[7] << 16);
    *(uint4*)(ohi + o) = uh;
    *(uint4*)(olo + o) = ul;
  }
}

// ---------------------------------------------------------------------------
// combine2: out[t] = part[kg0]+part[kg1]+bias + out[t] (residual=curr). NCHW.
// ---------------------------------------------------------------------------
__global__ __launch_bounds__(256) void combine2(
    const float* __restrict__ part, const float* __restrict__ bias,
    float* __restrict__ out_t) {
  int id = blockIdx.x * 256 + threadIdx.x;
  if (id >= N_ * C_ * HW_) return;
  int hw = id % HW_;
  int oc = (id / HW_) % C_;
  int n  = id / (HW_ * C_);
  long o = (long)n * T_ * C_ * HW_ + (long)oc * HW_ + hw;
  float v = part[((long)(n * 2 + 0) * 64 + oc) * HW_ + hw]
          + part[((long)(n * 2 + 1) * 64 + oc) * HW_ + hw]
          + bias[oc] + out_t[o];
  out_t[o] = v;
}

// ---------------------------------------------------------------------------
// Host-side orchestration
// ---------------------------------------------------------------------------
struct Bufs {
  float* f2t; float* part;
  short *xhi, *xlo, *h1hi, *h1lo, *w1hi, *w1lo, *w2hi, *w2lo;
};

static void run_step(float* out, const float* flows, int t, bool fwd, int i,
                     const float* b1, const float* b2, const Bufs& B,
                     hipStream_t stream) {
  const float* curr = out + (long)t * C_ * HW_;
  const float* p1 = nullptr;
  const float* p2 = nullptr;
  const float* f1 = nullptr;
  const float* f2 = nullptr;
  if (fwd) {
    if (t >= 1) { p1 = out + (long)(t - 1) * C_ * HW_; f1 = flows + (long)(t - 1) * 2 * HW_; }
    if (t >= 2) { p2 = out + (long)(t - 2) * C_ * HW_; f2 = flows + (long)(t - 2) * 2 * HW_; }
  } else {
    if (i >= 1) { p1 = out + (long)(t + 1) * C_ * HW_; f1 = flows + (long)(t + 1) * 2 * HW_; }
    if (i >= 2) { p2 = out + (long)(t + 2) * C_ * HW_; f2 = flows + (long)(t + 2) * 2 * HW_; }
  }

  if (p2) {
    int nb = (N_ * HW_ + 255) / 256;
    f2tot_kernel<<<nb, 256, 0, stream>>>(f1, f2, B.f2t);
  }
  warp_pack<<<N_ * 12 * H_, 256, 0, stream>>>(curr, p1, p2, f1, B.f2t, B.xhi, B.xlo);
  conv_mfma_p<12, 2><<<dim3(4, 56, N_ * 2), 256, 0, stream>>>(
      B.xhi, B.xlo, B.w1hi, B.w1lo, B.part);
  combine1<<<N_ * 4 * H_, 256, 0, stream>>>(B.part, b1, B.h1hi, B.h1lo);
  conv_mfma_p<4, 2><<<dim3(4, 56, N_ * 2), 256, 0, stream>>>(
      B.h1hi, B.h1lo, B.w2hi, B.w2lo, B.part);
  combine2<<<(N_ * C_ * HW_ + 255) / 256, 256, 0, stream>>>(
      B.part, b2, out + (long)t * C_ * HW_);
}

extern "C" void kernel_launch(void* const* d_in, const int* in_sizes, int n_in,
                              void* d_out, int out_size, void* d_ws, size_t ws_size,
                              hipStream_t stream) {
  const float* feats = (const float*)d_in[0];
  const float* fflow = (const float*)d_in[1];
  const float* bflow = (const float*)d_in[2];
  const float* W1 = (const float*)d_in[3];
  const float* b1 = (const float*)d_in[4];
  const float* W2 = (const float*)d_in[5];
  const float* b2 = (const float*)d_in[6];
  float* out = (float*)d_out;

  char* p = (char*)d_ws;
  auto carve = [&](size_t bytes) {
    void* r = (void*)p;
    p += (bytes + 255) & ~(size_t)255;
    return r;
  };
  Bufs B;
  size_t xpack_sh  = (size_t)N_ * 12 * PPX_ * 16;  // shorts per buffer
  size_t h1pack_sh = (size_t)N_ * 4 * PPX_ * 16;
  B.f2t  = (float*)carve(sizeof(float) * N_ * 2 * HW_);
  B.part = (float*)carve(sizeof(float) * (size_t)2 * N_ * 64 * HW_);
  B.xhi  = (short*)carve(2 * xpack_sh);
  B.xlo  = (short*)carve(2 * xpack_sh);
  B.h1hi = (short*)carve(2 * h1pack_sh);
  B.h1lo = (short*)carve(2 * h1pack_sh);
  B.w1hi = (short*)carve(2 * (size_t)(2 * 9 * 12 * 64 * 8));
  B.w1lo = (short*)carve(2 * (size_t)(2 * 9 * 12 * 64 * 8));
  B.w2hi = (short*)carve(2 * (size_t)(2 * 9 * 4 * 64 * 8));
  B.w2lo = (short*)carve(2 * (size_t)(2 * 9 * 4 * 64 * 8));

  // Zero packed buffers once per launch (zeros the conv padding halos).
  hipMemsetAsync(B.xhi, 0, 2 * xpack_sh, stream);
  hipMemsetAsync(B.xlo, 0, 2 * xpack_sh, stream);
  hipMemsetAsync(B.h1hi, 0, 2 * h1pack_sh, stream);
  hipMemsetAsync(B.h1lo, 0, 2 * h1pack_sh, stream);

  // Weight fragments (hi/lo split), once per launch.
  pack_w<<<(2 * 9 * 12 * 64 * 8 + 255) / 256, 256, 0, stream>>>(W1, B.w1hi, B.w1lo, 12);
  pack_w<<<(2 * 9 * 4 * 64 * 8 + 255) / 256, 256, 0, stream>>>(W2, B.w2hi, B.w2lo, 4);

  // Seed the working feats (in d_out) with the input feats.
  hipMemcpyAsync(out, feats, sizeof(float) * (size_t)N_ * T_ * C_ * HW_,
                 hipMemcpyDeviceToDevice, stream);

  for (int t = 0; t < T_; ++t)
    run_step(out, fflow, t, true, t, b1, b2, B, stream);
  for (int i = 0; i < T_; ++i) {
    int t = T_ - 1 - i;
    run_step(out, bflow, t, false, i, b1, b2, B, stream);
  }
}